// Round 3
// baseline (526.130 us; speedup 1.0000x reference)
//
#include <hip/hip_runtime.h>

#define BDIM 256
#define LDP 68          // padded LDS row stride (floats) for fp32 kernels

#define NB 8
#define NC 192
#define NN 3136         // 56*56 = 49*64
#define NCH 384
#define NK 9
#define MSEG 7          // m-sweep split factor for K2
#define NROW (NB * NN)  // 25088

typedef __attribute__((ext_vector_type(8))) short short8;
typedef __attribute__((ext_vector_type(4))) float f32x4;

__device__ __forceinline__ unsigned short f2bf(float f) {
  union { float f; unsigned u; } x{f};
  unsigned r = x.u + 0x7fff + ((x.u >> 16) & 1);  // RNE
  return (unsigned short)(r >> 16);
}

__device__ __forceinline__ void fma16(float acc[4][4], float4 av, float4 bv) {
  float an[4] = {av.x, av.y, av.z, av.w};
  float bm[4] = {bv.x, bv.y, bv.z, bv.w};
#pragma unroll
  for (int q = 0; q < 4; ++q)
#pragma unroll
    for (int r = 0; r < 4; ++r) acc[q][r] = fmaf(an[q], bm[r], acc[q][r]);
}

// ---------- K0: gcwb[768][192] bf16 <- gc_w split (rows 0-383: W1, 384-767: W2) ----------
__global__ __launch_bounds__(BDIM) void k0_convw(const float* __restrict__ gw,
                                                 unsigned short* __restrict__ gcwb) {
  int i = (blockIdx.x * BDIM + threadIdx.x) * 4;  // 147456 total elems
  int o = i / NC;
  int k = i - o * NC;
  const float* src = gw + (size_t)(o < NCH ? o : o - NCH) * (2 * NC) + (o < NCH ? 0 : NC) + k;
  float4 v = *(const float4*)src;
  uint2 u;
  u.x = (unsigned)f2bf(v.x) | ((unsigned)f2bf(v.y) << 16);
  u.y = (unsigned)f2bf(v.z) | ((unsigned)f2bf(v.w) << 16);
  *(uint2*)&gcwb[i] = u;
}

// ---------- K1: fp32 GEMM fc1 + BN1; emits hnb = bf16(normalize(h)) and norm ----------
__global__ __launch_bounds__(BDIM) void k1_fc1bn(
    const float* __restrict__ x, const float* __restrict__ w,
    const float* __restrict__ bias, const float* __restrict__ g1,
    const float* __restrict__ b1, const float* __restrict__ m1,
    const float* __restrict__ v1, unsigned short* __restrict__ hnb,
    float* __restrict__ normo) {
  __shared__ __align__(16) float a[64 * LDP];   // [k][n]
  __shared__ __align__(16) float wl[64 * LDP];  // [k][col]
  __shared__ float ns[64];
  int t = threadIdx.x;
  int b = blockIdx.x / 49, n0 = (blockIdx.x % 49) * 64;
  const float* xb = x + (size_t)b * NC * NN;
  int tx = t & 15, ty = t >> 4;
  if (t < 64) ns[t] = 0.f;
  float acc[3][4][4];
#pragma unroll
  for (int cp = 0; cp < 3; ++cp)
#pragma unroll
    for (int q = 0; q < 4; ++q)
#pragma unroll
      for (int r = 0; r < 4; ++r) acc[cp][q][r] = 0.f;

  for (int kc = 0; kc < 3; ++kc) {
    __syncthreads();
    for (int i = t; i < 1024; i += BDIM) {
      int k_ = i >> 4, n4 = (i & 15) << 2;
      float4 ld = *(const float4*)&xb[(size_t)(kc * 64 + k_) * NN + n0 + n4];
      *(float4*)&a[k_ * LDP + n4] = ld;
    }
    for (int cp = 0; cp < 3; ++cp) {
      __syncthreads();
      for (int i = t; i < 1024; i += BDIM) {
        int col_ = i >> 4, k4 = (i & 15) << 2;
        float4 ld = *(const float4*)&w[(size_t)(cp * 64 + col_) * NC + kc * 64 + k4];
        wl[(k4 + 0) * LDP + col_] = ld.x;
        wl[(k4 + 1) * LDP + col_] = ld.y;
        wl[(k4 + 2) * LDP + col_] = ld.z;
        wl[(k4 + 3) * LDP + col_] = ld.w;
      }
      __syncthreads();
#pragma unroll 4
      for (int c = 0; c < 64; ++c) {
        float4 av = *(const float4*)&a[c * LDP + ty * 4];
        float4 bv = *(const float4*)&wl[c * LDP + tx * 4];
        fma16(acc[cp], av, bv);
      }
    }
  }
  size_t rowb = (size_t)(b * NN + n0);
#pragma unroll
  for (int q = 0; q < 4; ++q) {
    float p = 0.f;
#pragma unroll
    for (int cp = 0; cp < 3; ++cp)
#pragma unroll
      for (int r = 0; r < 4; ++r) {
        int c = cp * 64 + tx * 4 + r;
        float s = g1[c] * rsqrtf(v1[c] + 1e-5f);
        float val = (acc[cp][q][r] + bias[c] - m1[c]) * s + b1[c];
        acc[cp][q][r] = val;
        p += val * val;
      }
    atomicAdd(&ns[ty * 4 + q], p);
  }
  __syncthreads();
  if (t < 64) {
    float s = fmaxf(sqrtf(ns[t]), 1e-12f);
    normo[rowb + t] = s;
    ns[t] = 1.f / s;
  }
  __syncthreads();
#pragma unroll
  for (int q = 0; q < 4; ++q) {
    float iv = ns[ty * 4 + q];
#pragma unroll
    for (int cp = 0; cp < 3; ++cp) {
      uint2 u;
      u.x = (unsigned)f2bf(acc[cp][q][0] * iv) | ((unsigned)f2bf(acc[cp][q][1] * iv) << 16);
      u.y = (unsigned)f2bf(acc[cp][q][2] * iv) | ((unsigned)f2bf(acc[cp][q][3] * iv) << 16);
      *(uint2*)&hnb[(rowb + ty * 4 + q) * (size_t)NC + cp * 64 + tx * 4] = u;
    }
  }
}

// shared staging macros (used by k2a and k3)
#define K2_DSW(BI)                                                          \
  {                                                                         \
    _Pragma("unroll") for (int i = 0; i < 6; ++i) {                         \
      int L = (i * 256 + t) * 16;                                           \
      int m_ = L / 384;                                                     \
      int kb_ = L - m_ * 384;                                               \
      *(short8*)&abuf[BI][m_ * 384 + (kb_ ^ ((m_ & 7) << 4))] = gr[i];      \
    }                                                                       \
  }

// ---------- K2a: sim = hn@hn^T via MFMA over m-segment, per-row top-9 candidates ----------
// block: 64 n (4 waves x 16), sweeps 7 of 49 m-tiles; emits 9 (val,idx) per n.
__global__ __launch_bounds__(BDIM) void k2a_mfma_topk(
    const unsigned short* __restrict__ hnb, float* __restrict__ candV,
    int* __restrict__ candI) {
  __shared__ __align__(16) unsigned char abuf[2][24576];
  int t = threadIdx.x;
  int bid = blockIdx.x;
  int b = bid / (49 * MSEG);
  int rem = bid % (49 * MSEG);
  int n0 = (rem / MSEG) * 64;
  int mseg = rem % MSEG;
  const unsigned short* hb = hnb + (size_t)b * NN * NC;
  int lane = t & 63, w = t >> 6;
  int l15 = lane & 15, l4 = lane >> 4;

  short8 bfr[6];
  {
    const short8* brow = (const short8*)(hb + (size_t)(n0 + w * 16 + l15) * NC + l4 * 8);
#pragma unroll
    for (int ks = 0; ks < 6; ++ks) bfr[ks] = brow[ks * 4];
  }
  float tv[NK];
  int ti[NK];
#pragma unroll
  for (int r = 0; r < NK; ++r) { tv[r] = -1e30f; ti[r] = 0x7fffffff; }

  short8 gr[6];
  const unsigned char* hbB = (const unsigned char*)hb;
#define K2_LOADG(MT)                                                        \
  {                                                                         \
    const unsigned char* src = hbB + (size_t)(MT) * 24576;                  \
    _Pragma("unroll") for (int i = 0; i < 6; ++i)                           \
        gr[i] = *(const short8*)(src + (i * 256 + t) * 16);                 \
  }
  K2_LOADG(mseg * MSEG);
  K2_DSW(0);
  for (int mt = 0; mt < MSEG; ++mt) {
    int mtg = mseg * MSEG + mt;
    int cur = mt & 1;
    if (mt < MSEG - 1) K2_LOADG(mtg + 1);
    __syncthreads();
#pragma unroll
    for (int sub = 0; sub < 4; ++sub) {
      int mrow = sub * 16 + l15;
      int rbase = mrow * 384, sw = (mrow & 7) << 4;
      f32x4 acc = {0.f, 0.f, 0.f, 0.f};
#pragma unroll
      for (int ks = 0; ks < 6; ++ks) {
        int kb = ks * 64 + l4 * 16;
        short8 af = *(const short8*)&abuf[cur][rbase + (kb ^ sw)];
        acc = __builtin_amdgcn_mfma_f32_16x16x32_bf16(af, bfr[ks], acc, 0, 0, 0);
      }
      int mbase = mtg * 64 + sub * 16 + l4 * 4;
#pragma unroll
      for (int r = 0; r < 4; ++r) {
        float v = acc[r];
        if (v > tv[8]) {  // per-lane m strictly ascending -> strict > keeps lowest-idx ties
          tv[8] = v;
          ti[8] = mbase + r;
#pragma unroll
          for (int s = 8; s >= 1; --s)
            if (tv[s] > tv[s - 1]) {
              float tf = tv[s]; tv[s] = tv[s - 1]; tv[s - 1] = tf;
              int tt = ti[s]; ti[s] = ti[s - 1]; ti[s - 1] = tt;
            }
        }
      }
    }
    if (mt < MSEG - 1) {
      __syncthreads();
      K2_DSW((mt + 1) & 1);
    }
  }
  __syncthreads();  // done with abuf as tiles; reuse for merge
  float* mvs = (float*)&abuf[0][0];  // 64 n x 4 lists x 9
  int* mis = (int*)&abuf[1][0];
  int slot = ((w * 16 + l15) * 4 + l4) * NK;
#pragma unroll
  for (int r = 0; r < NK; ++r) { mvs[slot + r] = tv[r]; mis[slot + r] = ti[r]; }
  __syncthreads();
  if (t < 64) {
    size_t row = (size_t)b * NN + n0 + t;
    float* v36 = &mvs[t * 36];
    int* i36 = &mis[t * 36];
    for (int r = 0; r < NK; ++r) {
      float bv = -1e30f;
      int bi = 0x7fffffff, bp = 0;
      for (int s = 0; s < 36; ++s) {
        float v = v36[s];
        int ii = i36[s];
        if (v > bv || (v == bv && ii < bi)) { bv = v; bi = ii; bp = s; }
      }
      candV[(size_t)(mseg * NK + r) * NROW + row] = bv;
      candI[(size_t)(mseg * NK + r) * NROW + row] = bi;
      v36[bp] = -2e30f;
    }
  }
}

// ---------- K2b: merge 63 candidates/row -> final top-9 indices ----------
__global__ __launch_bounds__(BDIM) void k2b_merge(const float* __restrict__ candV,
                                                  const int* __restrict__ candI,
                                                  int* __restrict__ idxo) {
  int row = blockIdx.x * BDIM + threadIdx.x;
  float tv[NK];
  int ti[NK];
#pragma unroll
  for (int r = 0; r < NK; ++r) { tv[r] = -1e30f; ti[r] = 0x7fffffff; }
  for (int s = 0; s < MSEG * NK; ++s) {
    float v = candV[(size_t)s * NROW + row];
    int ii = candI[(size_t)s * NROW + row];
    if (v > tv[8] || (v == tv[8] && ii < ti[8])) {
      tv[8] = v;
      ti[8] = ii;
#pragma unroll
      for (int r = 8; r >= 1; --r)
        if (tv[r] > tv[r - 1] || (tv[r] == tv[r - 1] && ti[r] < ti[r - 1])) {
          float tf = tv[r]; tv[r] = tv[r - 1]; tv[r - 1] = tf;
          int tt = ti[r]; ti[r] = ti[r - 1]; ti[r - 1] = tt;
        }
    }
  }
#pragma unroll
  for (int r = 0; r < NK; ++r) idxo[(size_t)row * NK + r] = ti[r];
}

// ---------- K3: P,Q = (hn @ gcwb^T) * norm  via MFMA ----------
__global__ __launch_bounds__(BDIM) void k3_pq_mfma(
    const unsigned short* __restrict__ hnb, const unsigned short* __restrict__ gcwb,
    const float* __restrict__ norm, float* __restrict__ P, float* __restrict__ Q) {
  __shared__ __align__(16) unsigned char abuf[2][24576];
  int t = threadIdx.x;
  int b = blockIdx.x / 49, n0 = (blockIdx.x % 49) * 64;
  const unsigned short* hb = hnb + (size_t)b * NN * NC;
  int lane = t & 63, w = t >> 6;
  int l15 = lane & 15, l4 = lane >> 4;
  int n = n0 + w * 16 + l15;
  short8 bfr[6];
  {
    const short8* brow = (const short8*)(hb + (size_t)n * NC + l4 * 8);
#pragma unroll
    for (int ks = 0; ks < 6; ++ks) bfr[ks] = brow[ks * 4];
  }
  float nrm = norm[(size_t)b * NN + n];
  size_t orow = (size_t)b * NN + n;
  short8 gr[6];
  const unsigned char* wB = (const unsigned char*)gcwb;
#define K3_LOADG(CH)                                                        \
  {                                                                         \
    const unsigned char* src = wB + (size_t)(CH) * 24576;                   \
    _Pragma("unroll") for (int i = 0; i < 6; ++i)                           \
        gr[i] = *(const short8*)(src + (i * 256 + t) * 16);                 \
  }
  K3_LOADG(0);
  K2_DSW(0);
  for (int ch = 0; ch < 12; ++ch) {
    int cur = ch & 1;
    if (ch < 11) K3_LOADG(ch + 1);
    __syncthreads();
#pragma unroll
    for (int sub = 0; sub < 4; ++sub) {
      int mrow = sub * 16 + l15;
      int rbase = mrow * 384, sw = (mrow & 7) << 4;
      f32x4 acc = {0.f, 0.f, 0.f, 0.f};
#pragma unroll
      for (int ks = 0; ks < 6; ++ks) {
        int kb = ks * 64 + l4 * 16;
        short8 af = *(const short8*)&abuf[cur][rbase + (kb ^ sw)];
        acc = __builtin_amdgcn_mfma_f32_16x16x32_bf16(af, bfr[ks], acc, 0, 0, 0);
      }
      int o = ch * 64 + sub * 16 + l4 * 4;
      f32x4 st = acc * nrm;
      float* dst = (o < NCH) ? P : Q;
      int oo = (o < NCH) ? o : o - NCH;
      *(f32x4*)&dst[orow * NCH + oo] = st;
    }
    if (ch < 11) {
      __syncthreads();
      K2_DSW((ch + 1) & 1);
    }
  }
}

// ---------- K4: m = gelu(BN2(P - Q + gc_b + max_k Q[idx_k])) ----------
__global__ __launch_bounds__(BDIM) void k4_gathermax(
    const float* __restrict__ P, const float* __restrict__ Q,
    const int* __restrict__ idx, const float* __restrict__ gcb,
    const float* __restrict__ g2, const float* __restrict__ b2,
    const float* __restrict__ m2, const float* __restrict__ v2,
    float* __restrict__ mb) {
  int t = threadIdx.x;
  int lane = t & 63, wv = t >> 6;
  int row = blockIdx.x * 4 + wv;
  int b = row / NN, n = row % NN;
  const int* ip = idx + (size_t)row * NK;
  int id[NK];
#pragma unroll
  for (int k = 0; k < NK; ++k) id[k] = ip[k];
  const float* Qb = Q + (size_t)b * NN * NCH;
  const float* Pr = P + (size_t)row * NCH;
  const float* Qr = Qb + (size_t)n * NCH;
#pragma unroll
  for (int j = 0; j < 6; ++j) {
    int o = j * 64 + lane;
    float mx = -1e30f;
#pragma unroll
    for (int k = 0; k < NK; ++k) mx = fmaxf(mx, Qb[(size_t)id[k] * NCH + o]);
    float e = Pr[o] - Qr[o] + gcb[o] + mx;
    float s = g2[o] * rsqrtf(v2[o] + 1e-5f);
    float y = (e - m2[o]) * s + b2[o];
    float ge = 0.5f * y * (1.f + erff(y * 0.70710678118654752f));
    mb[(size_t)row * NCH + o] = ge;
  }
}

// ---------- K5: out = BN3(m @ fc2_w^T + b) + shortcut, transposed to (B,C,N) ----------
__global__ __launch_bounds__(BDIM) void k5_fc2out(
    const float* __restrict__ mbuf, const float* __restrict__ w,
    const float* __restrict__ bias, const float* __restrict__ g3,
    const float* __restrict__ b3, const float* __restrict__ m3,
    const float* __restrict__ v3, const float* __restrict__ x,
    float* __restrict__ out) {
  __shared__ __align__(16) float a[64 * LDP];
  __shared__ __align__(16) float wl[64 * LDP];
  int t = threadIdx.x;
  int b = blockIdx.x / 49, n0 = (blockIdx.x % 49) * 64;
  const float* mbb = mbuf + (size_t)b * NN * NCH;
  int tx = t & 15, ty = t >> 4;
  float acc[3][4][4];
#pragma unroll
  for (int cp = 0; cp < 3; ++cp)
#pragma unroll
    for (int q = 0; q < 4; ++q)
#pragma unroll
      for (int r = 0; r < 4; ++r) acc[cp][q][r] = 0.f;

  for (int kc = 0; kc < 6; ++kc) {
    __syncthreads();
    for (int i = t; i < 1024; i += BDIM) {
      int n_ = i >> 4, c4 = (i & 15) << 2;
      float4 ld = *(const float4*)&mbb[(size_t)(n0 + n_) * NCH + kc * 64 + c4];
      a[(c4 + 0) * LDP + n_] = ld.x;
      a[(c4 + 1) * LDP + n_] = ld.y;
      a[(c4 + 2) * LDP + n_] = ld.z;
      a[(c4 + 3) * LDP + n_] = ld.w;
    }
    for (int cp = 0; cp < 3; ++cp) {
      __syncthreads();
      for (int i = t; i < 1024; i += BDIM) {
        int col_ = i >> 4, k4 = (i & 15) << 2;
        float4 ld = *(const float4*)&w[(size_t)(cp * 64 + col_) * NCH + kc * 64 + k4];
        wl[(k4 + 0) * LDP + col_] = ld.x;
        wl[(k4 + 1) * LDP + col_] = ld.y;
        wl[(k4 + 2) * LDP + col_] = ld.z;
        wl[(k4 + 3) * LDP + col_] = ld.w;
      }
      __syncthreads();
#pragma unroll 4
      for (int c = 0; c < 64; ++c) {
        float4 av = *(const float4*)&a[c * LDP + ty * 4];
        float4 bv = *(const float4*)&wl[c * LDP + tx * 4];
        fma16(acc[cp], av, bv);
      }
    }
  }
  const float* xb = x + (size_t)b * NC * NN;
  float* ob = out + (size_t)b * NC * NN;
  for (int cp = 0; cp < 3; ++cp) {
    __syncthreads();
#pragma unroll
    for (int q = 0; q < 4; ++q)
#pragma unroll
      for (int r = 0; r < 4; ++r) {
        int c = cp * 64 + tx * 4 + r;
        float s = g3[c] * rsqrtf(v3[c] + 1e-5f);
        float val = (acc[cp][q][r] + bias[c] - m3[c]) * s + b3[c];
        wl[(tx * 4 + r) * LDP + ty * 4 + q] = val;
      }
    __syncthreads();
    for (int i = t; i < 4096; i += BDIM) {
      int c_ = i >> 6, n_ = i & 63;
      size_t off = (size_t)(cp * 64 + c_) * NN + n0 + n_;
      ob[off] = wl[c_ * LDP + n_] + xb[off];
    }
  }
}

extern "C" void kernel_launch(void* const* d_in, const int* in_sizes, int n_in,
                              void* d_out, int out_size, void* d_ws, size_t ws_size,
                              hipStream_t stream) {
  const float* x = (const float*)d_in[0];
  const float* fc1_w = (const float*)d_in[1];
  const float* fc1_b = (const float*)d_in[2];
  const float* bn1_g = (const float*)d_in[3];
  const float* bn1_b = (const float*)d_in[4];
  const float* bn1_m = (const float*)d_in[5];
  const float* bn1_v = (const float*)d_in[6];
  const float* gc_w = (const float*)d_in[7];
  const float* gc_b = (const float*)d_in[8];
  const float* bn2_g = (const float*)d_in[9];
  const float* bn2_b = (const float*)d_in[10];
  const float* bn2_m = (const float*)d_in[11];
  const float* bn2_v = (const float*)d_in[12];
  const float* fc2_w = (const float*)d_in[13];
  const float* fc2_b = (const float*)d_in[14];
  const float* bn3_g = (const float*)d_in[15];
  const float* bn3_b = (const float*)d_in[16];
  const float* bn3_m = (const float*)d_in[17];
  const float* bn3_v = (const float*)d_in[18];

  // workspace (~127 MB): P | Q | mb | norm | idx | hnb | gcwb
  // candV/candI alias mb (k2a/k2b finish before k4 writes mb)
  float* ws = (float*)d_ws;
  size_t nrow = (size_t)NROW;
  size_t npq = (size_t)NB * NN * NCH;
  size_t nhb = (size_t)NB * NN * NC;
  float* P = ws;
  float* Q = P + npq;
  float* mb = Q + npq;
  float* norm = mb + npq;
  int* idx = (int*)(norm + nrow);
  unsigned short* hnb = (unsigned short*)(idx + nrow * NK);
  unsigned short* gcwb = hnb + nhb;
  float* candV = mb;
  int* candI = (int*)(mb + (size_t)MSEG * NK * NROW);

  k0_convw<<<144, BDIM, 0, stream>>>(gc_w, gcwb);
  k1_fc1bn<<<NB * 49, BDIM, 0, stream>>>(x, fc1_w, fc1_b, bn1_g, bn1_b, bn1_m,
                                         bn1_v, hnb, norm);
  k2a_mfma_topk<<<NB * 49 * MSEG, BDIM, 0, stream>>>(hnb, candV, candI);
  k2b_merge<<<NROW / BDIM, BDIM, 0, stream>>>(candV, candI, idx);
  k3_pq_mfma<<<NB * 49, BDIM, 0, stream>>>(hnb, gcwb, norm, P, Q);
  k4_gathermax<<<(NB * NN) / 4, BDIM, 0, stream>>>(P, Q, idx, gc_b, bn2_g,
                                                   bn2_b, bn2_m, bn2_v, mb);
  k5_fc2out<<<NB * 49, BDIM, 0, stream>>>(mb, fc2_w, fc2_b, bn3_g, bn3_b,
                                          bn3_m, bn3_v, x, (float*)d_out);
}

// Round 4
// 443.698 us; speedup vs baseline: 1.1858x; 1.1858x over previous
//
#include <hip/hip_runtime.h>

#define BDIM 256
#define LDP 68          // padded LDS row stride (floats) for fp32 kernels

#define NB 8
#define NC 192
#define NN 3136         // 56*56 = 49*64
#define NCH 384
#define NK 9
#define MSEG 7          // m-sweep split factor for K2 (49 = 7*7 tiles)
#define NROW (NB * NN)  // 25088

typedef __attribute__((ext_vector_type(8))) short short8;
typedef __attribute__((ext_vector_type(4))) float f32x4;

__device__ __forceinline__ unsigned short f2bf(float f) {
  union { float f; unsigned u; } x{f};
  unsigned r = x.u + 0x7fff + ((x.u >> 16) & 1);  // RNE
  return (unsigned short)(r >> 16);
}

// sortable-u32 transform of float bits: order-preserving for all finite values
__device__ __forceinline__ unsigned fsort(float f) {
  union { float f; unsigned u; } x{f};
  return x.u ^ ((unsigned)(((int)x.u) >> 31) | 0x80000000u);
}

__device__ __forceinline__ void fma16(float acc[4][4], float4 av, float4 bv) {
  float an[4] = {av.x, av.y, av.z, av.w};
  float bm[4] = {bv.x, bv.y, bv.z, bv.w};
#pragma unroll
  for (int q = 0; q < 4; ++q)
#pragma unroll
    for (int r = 0; r < 4; ++r) acc[q][r] = fmaf(an[q], bm[r], acc[q][r]);
}

// ---------- K0: gcwb[768][192] bf16 <- gc_w split (rows 0-383: W1, 384-767: W2) ----------
__global__ __launch_bounds__(BDIM) void k0_convw(const float* __restrict__ gw,
                                                 unsigned short* __restrict__ gcwb) {
  int i = (blockIdx.x * BDIM + threadIdx.x) * 4;  // 147456 total elems
  int o = i / NC;
  int k = i - o * NC;
  const float* src = gw + (size_t)(o < NCH ? o : o - NCH) * (2 * NC) + (o < NCH ? 0 : NC) + k;
  float4 v = *(const float4*)src;
  uint2 u;
  u.x = (unsigned)f2bf(v.x) | ((unsigned)f2bf(v.y) << 16);
  u.y = (unsigned)f2bf(v.z) | ((unsigned)f2bf(v.w) << 16);
  *(uint2*)&gcwb[i] = u;
}

// ---------- K1: fp32 GEMM fc1 + BN1; emits hnb = bf16(normalize(h)) and norm ----------
__global__ __launch_bounds__(BDIM) void k1_fc1bn(
    const float* __restrict__ x, const float* __restrict__ w,
    const float* __restrict__ bias, const float* __restrict__ g1,
    const float* __restrict__ b1, const float* __restrict__ m1,
    const float* __restrict__ v1, unsigned short* __restrict__ hnb,
    float* __restrict__ normo) {
  __shared__ __align__(16) float a[64 * LDP];   // [k][n]
  __shared__ __align__(16) float wl[64 * LDP];  // [k][col]
  __shared__ float ns[64];
  int t = threadIdx.x;
  int b = blockIdx.x / 49, n0 = (blockIdx.x % 49) * 64;
  const float* xb = x + (size_t)b * NC * NN;
  int tx = t & 15, ty = t >> 4;
  if (t < 64) ns[t] = 0.f;
  float acc[3][4][4];
#pragma unroll
  for (int cp = 0; cp < 3; ++cp)
#pragma unroll
    for (int q = 0; q < 4; ++q)
#pragma unroll
      for (int r = 0; r < 4; ++r) acc[cp][q][r] = 0.f;

  for (int kc = 0; kc < 3; ++kc) {
    __syncthreads();
    for (int i = t; i < 1024; i += BDIM) {
      int k_ = i >> 4, n4 = (i & 15) << 2;
      float4 ld = *(const float4*)&xb[(size_t)(kc * 64 + k_) * NN + n0 + n4];
      *(float4*)&a[k_ * LDP + n4] = ld;
    }
    for (int cp = 0; cp < 3; ++cp) {
      __syncthreads();
      for (int i = t; i < 1024; i += BDIM) {
        int col_ = i >> 4, k4 = (i & 15) << 2;
        float4 ld = *(const float4*)&w[(size_t)(cp * 64 + col_) * NC + kc * 64 + k4];
        wl[(k4 + 0) * LDP + col_] = ld.x;
        wl[(k4 + 1) * LDP + col_] = ld.y;
        wl[(k4 + 2) * LDP + col_] = ld.z;
        wl[(k4 + 3) * LDP + col_] = ld.w;
      }
      __syncthreads();
#pragma unroll 4
      for (int c = 0; c < 64; ++c) {
        float4 av = *(const float4*)&a[c * LDP + ty * 4];
        float4 bv = *(const float4*)&wl[c * LDP + tx * 4];
        fma16(acc[cp], av, bv);
      }
    }
  }
  size_t rowb = (size_t)(b * NN + n0);
#pragma unroll
  for (int q = 0; q < 4; ++q) {
    float p = 0.f;
#pragma unroll
    for (int cp = 0; cp < 3; ++cp)
#pragma unroll
      for (int r = 0; r < 4; ++r) {
        int c = cp * 64 + tx * 4 + r;
        float s = g1[c] * rsqrtf(v1[c] + 1e-5f);
        float val = (acc[cp][q][r] + bias[c] - m1[c]) * s + b1[c];
        acc[cp][q][r] = val;
        p += val * val;
      }
    atomicAdd(&ns[ty * 4 + q], p);
  }
  __syncthreads();
  if (t < 64) {
    float s = fmaxf(sqrtf(ns[t]), 1e-12f);
    normo[rowb + t] = s;
    ns[t] = 1.f / s;
  }
  __syncthreads();
#pragma unroll
  for (int q = 0; q < 4; ++q) {
    float iv = ns[ty * 4 + q];
#pragma unroll
    for (int cp = 0; cp < 3; ++cp) {
      uint2 u;
      u.x = (unsigned)f2bf(acc[cp][q][0] * iv) | ((unsigned)f2bf(acc[cp][q][1] * iv) << 16);
      u.y = (unsigned)f2bf(acc[cp][q][2] * iv) | ((unsigned)f2bf(acc[cp][q][3] * iv) << 16);
      *(uint2*)&hnb[(rowb + ty * 4 + q) * (size_t)NC + cp * 64 + tx * 4] = u;
    }
  }
}

// ---------- K2a: sim top-9 via MFMA, branchless packed-key selection ----------
// key = sortable_f32_top20 | (4095 - m). No LDS in main loop; m-side A-frags
// streamed per-lane from global (L1/L2-resident); n-side B-frags VGPR-resident.
__global__ __launch_bounds__(BDIM) void k2a_mfma_topk(
    const unsigned short* __restrict__ hnb, unsigned* __restrict__ candK) {
  __shared__ unsigned mkeys[64 * 36];
  int t = threadIdx.x;
  int bid = blockIdx.x;
  int b = bid / (49 * MSEG);
  int rem = bid % (49 * MSEG);
  int n0 = (rem / MSEG) * 64;
  int mseg = rem % MSEG;
  const unsigned short* hb = hnb + (size_t)b * NN * NC;
  int lane = t & 63, w = t >> 6;
  int l15 = lane & 15, l4 = lane >> 4;

  // B frag (n-side), resident: n = n0 + w*16 + l15, k = ks*32 + l4*8 + j
  short8 bfr[6];
  {
    const short8* brow = (const short8*)(hb + (size_t)(n0 + w * 16 + l15) * NC + l4 * 8);
#pragma unroll
    for (int ks = 0; ks < 6; ++ks) bfr[ks] = brow[ks * 4];
  }
  unsigned tk[NK];
#pragma unroll
  for (int r = 0; r < NK; ++r) tk[r] = 0u;

  // A frag (m-side) per-lane global address: row = mtile*64 + sub*16 + l15
  const char* pb = (const char*)hb + (size_t)mseg * MSEG * 24576 + l15 * 384 + l4 * 16;
  for (int mt = 0; mt < MSEG; ++mt) {
    const char* pt = pb + mt * 24576;
    int mbase = (mseg * MSEG + mt) * 64 + l4 * 4;
#pragma unroll
    for (int sub = 0; sub < 4; ++sub) {
      const char* ps = pt + sub * 6144;
      short8 af[6];
#pragma unroll
      for (int ks = 0; ks < 6; ++ks) af[ks] = *(const short8*)(ps + ks * 64);
      f32x4 acc = {0.f, 0.f, 0.f, 0.f};
#pragma unroll
      for (int ks = 0; ks < 6; ++ks)
        acc = __builtin_amdgcn_mfma_f32_16x16x32_bf16(af[ks], bfr[ks], acc, 0, 0, 0);
      int mknd = 4095 - (mbase + sub * 16);  // key low-bits base (lower m -> higher key)
#pragma unroll
      for (int r = 0; r < 4; ++r) {
        unsigned cur = (fsort(acc[r]) & 0xFFFFF000u) | (unsigned)(mknd - r);
#pragma unroll
        for (int j = 0; j < NK; ++j) {
          unsigned hi = tk[j] > cur ? tk[j] : cur;
          unsigned lo = tk[j] > cur ? cur : tk[j];
          tk[j] = hi;
          cur = lo;
        }
      }
    }
  }
  // merge 4 per-lane lists per n-row via LDS
  int nl = w * 16 + l15;
#pragma unroll
  for (int r = 0; r < NK; ++r) mkeys[(nl * 4 + l4) * NK + r] = tk[r];
  __syncthreads();
  if (t < 64) {
    const unsigned* k36 = &mkeys[t * 36];
    unsigned best[NK];
#pragma unroll
    for (int r = 0; r < NK; ++r) best[r] = 0u;
    for (int s = 0; s < 36; ++s) {
      unsigned cur = k36[s];
#pragma unroll
      for (int j = 0; j < NK; ++j) {
        unsigned hi = best[j] > cur ? best[j] : cur;
        unsigned lo = best[j] > cur ? cur : best[j];
        best[j] = hi;
        cur = lo;
      }
    }
    size_t row = (size_t)b * NN + n0 + t;
#pragma unroll
    for (int r = 0; r < NK; ++r) candK[(size_t)(mseg * NK + r) * NROW + row] = best[r];
  }
}

// ---------- K2b: merge 63 keys/row -> final top-9 indices ----------
__global__ __launch_bounds__(BDIM) void k2b_merge(const unsigned* __restrict__ candK,
                                                  int* __restrict__ idxo) {
  int row = blockIdx.x * BDIM + threadIdx.x;
  unsigned tk[NK];
#pragma unroll
  for (int r = 0; r < NK; ++r) tk[r] = 0u;
  for (int s = 0; s < MSEG * NK; ++s) {
    unsigned cur = candK[(size_t)s * NROW + row];
#pragma unroll
    for (int j = 0; j < NK; ++j) {
      unsigned hi = tk[j] > cur ? tk[j] : cur;
      unsigned lo = tk[j] > cur ? cur : tk[j];
      tk[j] = hi;
      cur = lo;
    }
  }
#pragma unroll
  for (int r = 0; r < NK; ++r)
    idxo[(size_t)row * NK + r] = 4095 - (int)(tk[r] & 4095u);
}

// shared staging macro (k3)
#define K2_DSW(BI)                                                          \
  {                                                                         \
    _Pragma("unroll") for (int i = 0; i < 6; ++i) {                         \
      int L = (i * 256 + t) * 16;                                           \
      int m_ = L / 384;                                                     \
      int kb_ = L - m_ * 384;                                               \
      *(short8*)&abuf[BI][m_ * 384 + (kb_ ^ ((m_ & 7) << 4))] = gr[i];      \
    }                                                                       \
  }

// ---------- K3: P,Q = (hn @ gcwb^T) * norm  via MFMA ----------
__global__ __launch_bounds__(BDIM) void k3_pq_mfma(
    const unsigned short* __restrict__ hnb, const unsigned short* __restrict__ gcwb,
    const float* __restrict__ norm, float* __restrict__ P, float* __restrict__ Q) {
  __shared__ __align__(16) unsigned char abuf[2][24576];
  int t = threadIdx.x;
  int b = blockIdx.x / 49, n0 = (blockIdx.x % 49) * 64;
  const unsigned short* hb = hnb + (size_t)b * NN * NC;
  int lane = t & 63, w = t >> 6;
  int l15 = lane & 15, l4 = lane >> 4;
  int n = n0 + w * 16 + l15;
  short8 bfr[6];
  {
    const short8* brow = (const short8*)(hb + (size_t)n * NC + l4 * 8);
#pragma unroll
    for (int ks = 0; ks < 6; ++ks) bfr[ks] = brow[ks * 4];
  }
  float nrm = norm[(size_t)b * NN + n];
  size_t orow = (size_t)b * NN + n;
  short8 gr[6];
  const unsigned char* wB = (const unsigned char*)gcwb;
#define K3_LOADG(CH)                                                        \
  {                                                                         \
    const unsigned char* src = wB + (size_t)(CH) * 24576;                   \
    _Pragma("unroll") for (int i = 0; i < 6; ++i)                           \
        gr[i] = *(const short8*)(src + (i * 256 + t) * 16);                 \
  }
  K3_LOADG(0);
  K2_DSW(0);
  for (int ch = 0; ch < 12; ++ch) {
    int cur = ch & 1;
    if (ch < 11) K3_LOADG(ch + 1);
    __syncthreads();
#pragma unroll
    for (int sub = 0; sub < 4; ++sub) {
      int mrow = sub * 16 + l15;
      int rbase = mrow * 384, sw = (mrow & 7) << 4;
      f32x4 acc = {0.f, 0.f, 0.f, 0.f};
#pragma unroll
      for (int ks = 0; ks < 6; ++ks) {
        int kb = ks * 64 + l4 * 16;
        short8 af = *(const short8*)&abuf[cur][rbase + (kb ^ sw)];
        acc = __builtin_amdgcn_mfma_f32_16x16x32_bf16(af, bfr[ks], acc, 0, 0, 0);
      }
      int o = ch * 64 + sub * 16 + l4 * 4;
      f32x4 st = acc * nrm;
      float* dst = (o < NCH) ? P : Q;
      int oo = (o < NCH) ? o : o - NCH;
      *(f32x4*)&dst[orow * NCH + oo] = st;
    }
    if (ch < 11) {
      __syncthreads();
      K2_DSW((ch + 1) & 1);
    }
  }
}

// ---------- K4: m = gelu(BN2(P - Q + gc_b + max_k Q[idx_k])) ----------
__global__ __launch_bounds__(BDIM) void k4_gathermax(
    const float* __restrict__ P, const float* __restrict__ Q,
    const int* __restrict__ idx, const float* __restrict__ gcb,
    const float* __restrict__ g2, const float* __restrict__ b2,
    const float* __restrict__ m2, const float* __restrict__ v2,
    float* __restrict__ mb) {
  int t = threadIdx.x;
  int lane = t & 63, wv = t >> 6;
  int row = blockIdx.x * 4 + wv;
  int b = row / NN, n = row % NN;
  const int* ip = idx + (size_t)row * NK;
  int id[NK];
#pragma unroll
  for (int k = 0; k < NK; ++k) id[k] = ip[k];
  const float* Qb = Q + (size_t)b * NN * NCH;
  const float* Pr = P + (size_t)row * NCH;
  const float* Qr = Qb + (size_t)n * NCH;
#pragma unroll
  for (int j = 0; j < 6; ++j) {
    int o = j * 64 + lane;
    float mx = -1e30f;
#pragma unroll
    for (int k = 0; k < NK; ++k) mx = fmaxf(mx, Qb[(size_t)id[k] * NCH + o]);
    float e = Pr[o] - Qr[o] + gcb[o] + mx;
    float s = g2[o] * rsqrtf(v2[o] + 1e-5f);
    float y = (e - m2[o]) * s + b2[o];
    float ge = 0.5f * y * (1.f + erff(y * 0.70710678118654752f));
    mb[(size_t)row * NCH + o] = ge;
  }
}

// ---------- K5: out = BN3(m @ fc2_w^T + b) + shortcut, transposed to (B,C,N) ----------
__global__ __launch_bounds__(BDIM) void k5_fc2out(
    const float* __restrict__ mbuf, const float* __restrict__ w,
    const float* __restrict__ bias, const float* __restrict__ g3,
    const float* __restrict__ b3, const float* __restrict__ m3,
    const float* __restrict__ v3, const float* __restrict__ x,
    float* __restrict__ out) {
  __shared__ __align__(16) float a[64 * LDP];
  __shared__ __align__(16) float wl[64 * LDP];
  int t = threadIdx.x;
  int b = blockIdx.x / 49, n0 = (blockIdx.x % 49) * 64;
  const float* mbb = mbuf + (size_t)b * NN * NCH;
  int tx = t & 15, ty = t >> 4;
  float acc[3][4][4];
#pragma unroll
  for (int cp = 0; cp < 3; ++cp)
#pragma unroll
    for (int q = 0; q < 4; ++q)
#pragma unroll
      for (int r = 0; r < 4; ++r) acc[cp][q][r] = 0.f;

  for (int kc = 0; kc < 6; ++kc) {
    __syncthreads();
    for (int i = t; i < 1024; i += BDIM) {
      int n_ = i >> 4, c4 = (i & 15) << 2;
      float4 ld = *(const float4*)&mbb[(size_t)(n0 + n_) * NCH + kc * 64 + c4];
      a[(c4 + 0) * LDP + n_] = ld.x;
      a[(c4 + 1) * LDP + n_] = ld.y;
      a[(c4 + 2) * LDP + n_] = ld.z;
      a[(c4 + 3) * LDP + n_] = ld.w;
    }
    for (int cp = 0; cp < 3; ++cp) {
      __syncthreads();
      for (int i = t; i < 1024; i += BDIM) {
        int col_ = i >> 4, k4 = (i & 15) << 2;
        float4 ld = *(const float4*)&w[(size_t)(cp * 64 + col_) * NCH + kc * 64 + k4];
        wl[(k4 + 0) * LDP + col_] = ld.x;
        wl[(k4 + 1) * LDP + col_] = ld.y;
        wl[(k4 + 2) * LDP + col_] = ld.z;
        wl[(k4 + 3) * LDP + col_] = ld.w;
      }
      __syncthreads();
#pragma unroll 4
      for (int c = 0; c < 64; ++c) {
        float4 av = *(const float4*)&a[c * LDP + ty * 4];
        float4 bv = *(const float4*)&wl[c * LDP + tx * 4];
        fma16(acc[cp], av, bv);
      }
    }
  }
  const float* xb = x + (size_t)b * NC * NN;
  float* ob = out + (size_t)b * NC * NN;
  for (int cp = 0; cp < 3; ++cp) {
    __syncthreads();
#pragma unroll
    for (int q = 0; q < 4; ++q)
#pragma unroll
      for (int r = 0; r < 4; ++r) {
        int c = cp * 64 + tx * 4 + r;
        float s = g3[c] * rsqrtf(v3[c] + 1e-5f);
        float val = (acc[cp][q][r] + bias[c] - m3[c]) * s + b3[c];
        wl[(tx * 4 + r) * LDP + ty * 4 + q] = val;
      }
    __syncthreads();
    for (int i = t; i < 4096; i += BDIM) {
      int c_ = i >> 6, n_ = i & 63;
      size_t off = (size_t)(cp * 64 + c_) * NN + n0 + n_;
      ob[off] = wl[c_ * LDP + n_] + xb[off];
    }
  }
}

extern "C" void kernel_launch(void* const* d_in, const int* in_sizes, int n_in,
                              void* d_out, int out_size, void* d_ws, size_t ws_size,
                              hipStream_t stream) {
  const float* x = (const float*)d_in[0];
  const float* fc1_w = (const float*)d_in[1];
  const float* fc1_b = (const float*)d_in[2];
  const float* bn1_g = (const float*)d_in[3];
  const float* bn1_b = (const float*)d_in[4];
  const float* bn1_m = (const float*)d_in[5];
  const float* bn1_v = (const float*)d_in[6];
  const float* gc_w = (const float*)d_in[7];
  const float* gc_b = (const float*)d_in[8];
  const float* bn2_g = (const float*)d_in[9];
  const float* bn2_b = (const float*)d_in[10];
  const float* bn2_m = (const float*)d_in[11];
  const float* bn2_v = (const float*)d_in[12];
  const float* fc2_w = (const float*)d_in[13];
  const float* fc2_b = (const float*)d_in[14];
  const float* bn3_g = (const float*)d_in[15];
  const float* bn3_b = (const float*)d_in[16];
  const float* bn3_m = (const float*)d_in[17];
  const float* bn3_v = (const float*)d_in[18];

  // workspace (~127 MB): P | Q | mb | norm | idx | hnb | gcwb
  // candK aliases mb (k2a/k2b finish before k4 writes mb)
  float* ws = (float*)d_ws;
  size_t nrow = (size_t)NROW;
  size_t npq = (size_t)NB * NN * NCH;
  size_t nhb = (size_t)NB * NN * NC;
  float* P = ws;
  float* Q = P + npq;
  float* mb = Q + npq;
  float* norm = mb + npq;
  int* idx = (int*)(norm + nrow);
  unsigned short* hnb = (unsigned short*)(idx + nrow * NK);
  unsigned short* gcwb = hnb + nhb;
  unsigned* candK = (unsigned*)mb;

  k0_convw<<<144, BDIM, 0, stream>>>(gc_w, gcwb);
  k1_fc1bn<<<NB * 49, BDIM, 0, stream>>>(x, fc1_w, fc1_b, bn1_g, bn1_b, bn1_m,
                                         bn1_v, hnb, norm);
  k2a_mfma_topk<<<NB * 49 * MSEG, BDIM, 0, stream>>>(hnb, candK);
  k2b_merge<<<NROW / BDIM, BDIM, 0, stream>>>(candK, idx);
  k3_pq_mfma<<<NB * 49, BDIM, 0, stream>>>(hnb, gcwb, norm, P, Q);
  k4_gathermax<<<(NB * NN) / 4, BDIM, 0, stream>>>(P, Q, idx, gc_b, bn2_g,
                                                   bn2_b, bn2_m, bn2_v, mb);
  k5_fc2out<<<NB * 49, BDIM, 0, stream>>>(mb, fc2_w, fc2_b, bn3_g, bn3_b,
                                          bn3_m, bn3_v, x, (float*)d_out);
}